// Round 10
// baseline (190.655 us; speedup 1.0000x reference)
//
#include <hip/hip_runtime.h>

#define NB 32
#define NC 256
#define NL 128   // NH+NW
#define NCM 128
#define NCO 256
#define SUBS 32             // blocks per batch

typedef float v4f __attribute__((ext_vector_type(4)));
typedef unsigned long long ull;

// Producer side only: agent-scope (sc0/sc1) stores land at the Infinity
// Cache (coherent point) when vmcnt retires — visible cross-XCD.
__device__ __forceinline__ void st_coh(float* p, float v) {
    __hip_atomic_store(p, v, __ATOMIC_RELAXED, __HIP_MEMORY_SCOPE_AGENT);
}
__device__ __forceinline__ void st_coh2(float* p, float a, float b) {
    ull u = (ull)__float_as_uint(a) | ((ull)__float_as_uint(b) << 32);
    __hip_atomic_store((ull*)p, u, __ATOMIC_RELAXED, __HIP_MEMORY_SCOPE_AGENT);
}

// Consumers use PLAIN vectorized loads: safe because (1) producers bypass
// L2 (sc1), (2) these lines are never plain-read before the barrier in
// this kernel, (3) dispatch boundaries invalidate L2 between replays.
// R8 post-mortem: scalar agent-scope loads (~800cy to IC, no L1/L2) were
// the 140us stall — NOT the barrier count.

__device__ __forceinline__ void batch_barrier(unsigned* cnt) {
    __syncthreads();   // drains vmcnt(0): all st_coh of this block retired
    if (threadIdx.x == 0) {
        __hip_atomic_fetch_add(cnt, 1u, __ATOMIC_RELAXED,
                               __HIP_MEMORY_SCOPE_AGENT);
        while (__hip_atomic_load(cnt, __ATOMIC_RELAXED,
                                 __HIP_MEMORY_SCOPE_AGENT) < (unsigned)SUBS)
            __builtin_amdgcn_s_sleep(2);
    }
    __syncthreads();
}

__global__ __launch_bounds__(256, 4) void k_ca(
    const float* __restrict__ x,
    const float* __restrict__ w1, const float* __restrict__ b1,
    const float* __restrict__ gam, const float* __restrict__ bet,
    const float* __restrict__ mu, const float* __restrict__ var,
    const float* __restrict__ w2, const float* __restrict__ b2,
    const float* __restrict__ w3, const float* __restrict__ b3,
    float* __restrict__ pool, float* __restrict__ a,
    float* __restrict__ gh, float* __restrict__ gw,
    unsigned* __restrict__ bar,
    float* __restrict__ out)
{
    const int blk = blockIdx.x;
    const int b   = blk >> 5;        // batch
    const int sub = blk & 31;        // 0..31 within batch
    const int t   = threadIdx.x;
    const int wid = t >> 6, lane = t & 63;
    __shared__ float smem[5120];     // 20 KB (phase 2 peak)

    // ---------- Phase 1: pooling, 8 planes/sub, 2 per wave, no syncthreads ----
    for (int p = 0; p < 2; ++p) {
        int plane = b * NC + sub * 8 + wid * 2 + p;
        const float4* px = (const float4*)(x + (size_t)plane * 4096);
        float* pp = pool + (size_t)plane * NL;
        float4 csum = make_float4(0.f, 0.f, 0.f, 0.f);
        #pragma unroll
        for (int i = 0; i < 16; ++i) {
            int f = lane + i * 64;               // f4 idx; row=f>>4, col4=f&15
            float4 v = px[f];
            csum.x += v.x; csum.y += v.y; csum.z += v.z; csum.w += v.w;
            float s = v.x + v.y + v.z + v.w;
            s += __shfl_xor(s, 1);
            s += __shfl_xor(s, 2);
            s += __shfl_xor(s, 4);
            s += __shfl_xor(s, 8);               // 16-lane group = one row
            if ((lane & 15) == 0)
                st_coh(&pp[(lane >> 4) + 4 * i], s * 0.015625f);    // xh
        }
        csum.x += __shfl_xor(csum.x, 16); csum.y += __shfl_xor(csum.y, 16);
        csum.z += __shfl_xor(csum.z, 16); csum.w += __shfl_xor(csum.w, 16);
        csum.x += __shfl_xor(csum.x, 32); csum.y += __shfl_xor(csum.y, 32);
        csum.z += __shfl_xor(csum.z, 32); csum.w += __shfl_xor(csum.w, 32);
        if (lane < 16) {                          // xw: cols 4*lane..+3
            st_coh2(&pp[64 + lane * 4],     csum.x * 0.015625f, csum.y * 0.015625f);
            st_coh2(&pp[64 + lane * 4 + 2], csum.z * 0.015625f, csum.w * 0.015625f);
        }
    }
    batch_barrier(&bar[b * 3 + 0]);

    // ---------- Phase 2: mlp1+BN+hswish; sub owns 4 m rows (all l) ----------
    {
        int m0 = sub * 4;
        float* w1s = smem;           // [4][256]
        float* ps  = smem + 1024;    // [32][128] chunk
        {   // stage w1 rows m0..m0+3 (one f4/thread)
            int r = t >> 6, c4 = t & 63;
            *(v4f*)&w1s[r * 256 + c4 * 4] =
                *(const v4f*)(w1 + (size_t)(m0 + r) * NC + c4 * 4);
        }
        const float* poolb = pool + (size_t)b * NC * NL;
        int tm2 = t >> 7, l = t & 127;           // m pair, l column
        float acc0 = 0.f, acc1 = 0.f;
        for (int cc = 0; cc < NC; cc += 32) {
            #pragma unroll
            for (int k = 0; k < 4; ++k) {        // stage pool chunk 32c x 128l
                int idx = t + k * 256;
                int ci = idx >> 5, l4 = idx & 31;
                *(v4f*)&ps[ci * 128 + l4 * 4] =
                    *(const v4f*)(poolb + (size_t)(cc + ci) * NL + l4 * 4);
            }
            __syncthreads();
            #pragma unroll
            for (int cj = 0; cj < 32; ++cj) {
                float pv = ps[cj * 128 + l];
                acc0 += w1s[(2 * tm2 + 0) * 256 + cc + cj] * pv;
                acc1 += w1s[(2 * tm2 + 1) * 256 + cc + cj] * pv;
            }
            __syncthreads();
        }
        #pragma unroll
        for (int i = 0; i < 2; ++i) {
            int m = m0 + 2 * tm2 + i;
            float scale = gam[m] * rsqrtf(var[m] + 1e-5f);
            float y = ((i ? acc1 : acc0) + b1[m] - mu[m]) * scale + bet[m];
            float hs = y * fminf(fmaxf(y + 3.f, 0.f), 6.f) * (1.f / 6.f);
            st_coh(&a[(size_t)b * NCM * NL + (size_t)m * NL + l], hs);
        }
    }
    batch_barrier(&bar[b * 3 + 1]);

    // ---------- Phase 3: gates; sub -> (side, 16 o rows) ----------
    {
        int side = sub >> 4, og = sub & 15, o0 = og * 16;
        const float* wsel = side ? w3 : w2;
        const float* bsel = side ? b3 : b2;
        float* gsel = side ? gw : gh;
        float* ws2 = smem;           // [16][128]
        float* as  = smem + 2048;    // [32][64] chunk
        #pragma unroll
        for (int k = 0; k < 2; ++k) {            // stage wsel rows o0..o0+15
            int idx = t + k * 256;
            int oi = idx >> 5, m4 = idx & 31;
            *(v4f*)&ws2[oi * 128 + m4 * 4] =
                *(const v4f*)(wsel + (size_t)(o0 + oi) * NCM + m4 * 4);
        }
        const float* ab = a + (size_t)b * NCM * NL + side * 64;
        int og2 = t >> 6, l = t & 63;
        float acc[4] = {};
        for (int kc = 0; kc < NCM; kc += 32) {
            #pragma unroll
            for (int k = 0; k < 2; ++k) {        // stage a chunk 32k x 64l
                int idx = t + k * 256;
                int ki = idx >> 4, l4 = idx & 15;
                *(v4f*)&as[ki * 64 + l4 * 4] =
                    *(const v4f*)(ab + (size_t)(kc + ki) * NL + l4 * 4);
            }
            __syncthreads();
            #pragma unroll
            for (int kj = 0; kj < 32; ++kj) {
                float av = as[kj * 64 + l];
                #pragma unroll
                for (int i = 0; i < 4; ++i)
                    acc[i] += ws2[(og2 * 4 + i) * 128 + kc + kj] * av;
            }
            __syncthreads();
        }
        #pragma unroll
        for (int i = 0; i < 4; ++i) {
            int o = o0 + og2 * 4 + i;
            float g = 1.f / (1.f + __expf(-(acc[i] + bsel[o])));
            st_coh(&gsel[((size_t)b * NCO + o) * 64 + l], g);
        }
    }
    batch_barrier(&bar[b * 3 + 2]);

    // ---------- Phase 4: apply, 8 planes/sub; plain loads for gates ----------
    {
        float* gsm = smem;           // [8][128]: gh | gw per plane
        int c0 = sub * 8;
        {
            int p = t >> 5, r = t & 31;
            size_t plane = (size_t)b * NC + c0 + p;
            v4f v = (r < 16) ? *(const v4f*)(gh + plane * 64 + r * 4)
                             : *(const v4f*)(gw + plane * 64 + (r - 16) * 4);
            *(v4f*)&gsm[p * 128 + ((r < 16) ? r * 4 : 64 + (r - 16) * 4)] = v;
        }
        __syncthreads();
        for (int p = 0; p < 8; ++p) {
            size_t plane = (size_t)b * NC + c0 + p;
            const float4* px = (const float4*)(x + plane * 4096);
            float4* po = (float4*)(out + plane * 4096);
            const float* ghp = &gsm[p * 128];
            const float4* gwp = (const float4*)&gsm[p * 128 + 64];
            #pragma unroll
            for (int i = 0; i < 4; ++i) {
                int f = t + i * 256;
                int row = f >> 4, w4 = f & 15;
                float4 v = px[f];
                float g = ghp[row];
                float4 gv = gwp[w4];
                v.x *= g * gv.x; v.y *= g * gv.y;
                v.z *= g * gv.z; v.w *= g * gv.w;
                po[f] = v;
            }
        }
    }
}

extern "C" void kernel_launch(void* const* d_in, const int* in_sizes, int n_in,
                              void* d_out, int out_size, void* d_ws, size_t ws_size,
                              hipStream_t stream) {
    const float* x   = (const float*)d_in[0];
    const float* w1  = (const float*)d_in[1];
    const float* b1  = (const float*)d_in[2];
    const float* gam = (const float*)d_in[3];
    const float* bet = (const float*)d_in[4];
    const float* mu  = (const float*)d_in[5];
    const float* var = (const float*)d_in[6];
    const float* w2  = (const float*)d_in[7];
    const float* b2  = (const float*)d_in[8];
    const float* w3  = (const float*)d_in[9];
    const float* b3  = (const float*)d_in[10];
    float* ws   = (float*)d_ws;
    float* pool = ws;                       // 32*256*128 = 1,048,576 f
    float* a    = ws + 1048576;             // 32*128*128 =   524,288 f
    float* gh   = ws + 1572864;             // 32*256*64  =   524,288 f
    float* gw   = ws + 2097152;             // 32*256*64  =   524,288 f
    unsigned* bar = (unsigned*)(ws + 2621440);   // 32*3 counters
    float* out  = (float*)d_out;

    hipMemsetAsync(bar, 0, NB * 3 * sizeof(unsigned), stream);
    k_ca<<<NB * SUBS, 256, 0, stream>>>(x, w1, b1, gam, bet, mu, var,
                                        w2, b2, w3, b3,
                                        pool, a, gh, gw, bar, out);
}

// Round 11
// 92.429 us; speedup vs baseline: 2.0627x; 2.0627x over previous
//
#include <hip/hip_runtime.h>

#define NB 32
#define NC 256
#define NL 128   // NH+NW
#define NCM 128
#define NCO 256
#define NPLANES (NB * NC)   // 8192

// ---------------- Kernel 1: H/W mean pooling (R6-proven) ----------------
// grid: 2048 blocks, 4 planes/block. pool layout: [b][c][l],
// l<64 = xh (mean over W), l>=64 = xw (mean over H)
__global__ __launch_bounds__(256) void k_pool(const float* __restrict__ x,
                                              float* __restrict__ pool) {
    int t = threadIdx.x;
    __shared__ float smem[1024];
    #pragma unroll
    for (int p = 0; p < 4; ++p) {
        int plane = blockIdx.x * 4 + p;          // b*NC + c
        const float4* px = (const float4*)(x + (size_t)plane * 4096);
        float4 csum = make_float4(0.f, 0.f, 0.f, 0.f);
        #pragma unroll
        for (int i = 0; i < 4; ++i) {
            int f = t + i * 256;                 // f4 idx; row=f>>4, col4=f&15
            float4 v = px[f];
            csum.x += v.x; csum.y += v.y; csum.z += v.z; csum.w += v.w;
            float s = v.x + v.y + v.z + v.w;
            s += __shfl_xor(s, 1);
            s += __shfl_xor(s, 2);
            s += __shfl_xor(s, 4);
            s += __shfl_xor(s, 8);               // 16-lane group = one row
            if ((t & 15) == 0)
                pool[(size_t)plane * NL + (t >> 4) + 16 * i] = s * 0.015625f; // xh
        }
        ((float4*)smem)[t] = csum;
        __syncthreads();
        if (t < 64) {
            float acc = 0.f;
            #pragma unroll
            for (int g = 0; g < 16; ++g)
                acc += smem[((t >> 2) + 16 * g) * 4 + (t & 3)];
            pool[(size_t)plane * NL + 64 + t] = acc * 0.015625f;  // xw
        }
        __syncthreads();
    }
}

// ---------------- Kernel 2: y = w1@pool + BN + hswish ----------------
// grid (NB, 16): 8 m-rows per block, 512 blocks. NO per-chunk staging or
// sync: w1 tile in LDS once; pool read straight from global, coalesced
// over l (lane = l-quad), one float4 + 4 FMA per K-step, fully pipelined.
__global__ __launch_bounds__(256) void k_mlp1(const float* __restrict__ pool,
                                              const float* __restrict__ w1,
                                              const float* __restrict__ b1,
                                              const float* __restrict__ gam,
                                              const float* __restrict__ bet,
                                              const float* __restrict__ mu,
                                              const float* __restrict__ var,
                                              float* __restrict__ a) {
    int b = blockIdx.x, m0 = blockIdx.y * 8;
    int t = threadIdx.x;
    __shared__ float w1s[8 * 256];               // 8 KB
    #pragma unroll
    for (int k = 0; k < 2; ++k) {                // stage w1 rows m0..m0+7
        int idx = t + k * 256;                   // 512 float4
        int r = idx >> 6, c4 = idx & 63;
        *(float4*)&w1s[r * 256 + c4 * 4] =
            *(const float4*)(w1 + (size_t)(m0 + r) * NC + c4 * 4);
    }
    __syncthreads();

    int l4 = t & 31;                             // l-quad: l = l4*4..+3
    int mh = t >> 5;                             // 0..7 -> m = m0+mh
    const float* pb = pool + (size_t)b * NC * NL + l4 * 4;
    const float* wr = &w1s[mh * 256];
    float acc[4] = {};
    #pragma unroll 8
    for (int c = 0; c < NC; ++c) {
        float4 pv = *(const float4*)(pb + (size_t)c * NL);
        float w = wr[c];                         // wave-uniform LDS broadcast
        acc[0] += w * pv.x; acc[1] += w * pv.y;
        acc[2] += w * pv.z; acc[3] += w * pv.w;
    }
    int m = m0 + mh;
    float scale = gam[m] * rsqrtf(var[m] + 1e-5f);
    float base  = b1[m] - mu[m];
    float bb    = bet[m];
    float r[4];
    #pragma unroll
    for (int j = 0; j < 4; ++j) {
        float y = (acc[j] + base) * scale + bb;
        r[j] = y * fminf(fmaxf(y + 3.f, 0.f), 6.f) * (1.f / 6.f);
    }
    *(float4*)(a + (size_t)b * NCM * NL + (size_t)m * NL + l4 * 4) =
        make_float4(r[0], r[1], r[2], r[3]);
}

// ---------------- Kernel 3: gh/gw = sigmoid(w@a + b) ----------------
// grid (NB, 2, 8): 32 o-rows per block, 512 blocks. Same LDS-free pattern.
__global__ __launch_bounds__(256) void k_gate(const float* __restrict__ a,
                                              const float* __restrict__ w2,
                                              const float* __restrict__ b2,
                                              const float* __restrict__ w3,
                                              const float* __restrict__ b3,
                                              float* __restrict__ gh,
                                              float* __restrict__ gw) {
    int b = blockIdx.x, side = blockIdx.y, o0 = blockIdx.z * 32;
    const float* wsel = side ? w3 : w2;
    const float* bsel = side ? b3 : b2;
    float* gsel = side ? gw : gh;
    int t = threadIdx.x;
    __shared__ float wsm[32 * 128];              // 16 KB
    #pragma unroll
    for (int k = 0; k < 4; ++k) {                // stage wsel rows o0..o0+31
        int idx = t + k * 256;                   // 1024 float4
        int r = idx >> 5, m4 = idx & 31;
        *(float4*)&wsm[r * 128 + m4 * 4] =
            *(const float4*)(wsel + (size_t)(o0 + r) * NCM + m4 * 4);
    }
    __syncthreads();

    int l4 = t & 15;                             // l-quad: l = l4*4..+3 (64 l)
    int oh = t >> 4;                             // 0..15 -> o = o0+oh*2+i
    const float* ab = a + (size_t)b * NCM * NL + side * 64 + l4 * 4;
    const float* w0 = &wsm[(oh * 2 + 0) * 128];
    const float* w1r = &wsm[(oh * 2 + 1) * 128];
    float acc[2][4] = {};
    #pragma unroll 8
    for (int m = 0; m < NCM; ++m) {
        float4 av = *(const float4*)(ab + (size_t)m * NL);
        float wa = w0[m], wb = w1r[m];           // wave-uniform broadcasts
        acc[0][0] += wa * av.x; acc[0][1] += wa * av.y;
        acc[0][2] += wa * av.z; acc[0][3] += wa * av.w;
        acc[1][0] += wb * av.x; acc[1][1] += wb * av.y;
        acc[1][2] += wb * av.z; acc[1][3] += wb * av.w;
    }
    #pragma unroll
    for (int i = 0; i < 2; ++i) {
        int o = o0 + oh * 2 + i;
        float bias = bsel[o];
        float g[4];
        #pragma unroll
        for (int j = 0; j < 4; ++j)
            g[j] = 1.f / (1.f + __expf(-(acc[i][j] + bias)));
        *(float4*)(gsel + ((size_t)b * NCO + o) * 64 + l4 * 4) =
            make_float4(g[0], g[1], g[2], g[3]);
    }
}

// ---------------- Kernel 4: out = x * gh[h] * gw[w] (R6-proven) ----------------
__global__ __launch_bounds__(256) void k_apply(const float* __restrict__ x,
                                               const float* __restrict__ gh,
                                               const float* __restrict__ gw,
                                               float* __restrict__ out) {
    int t = threadIdx.x;
    #pragma unroll
    for (int p = 0; p < 2; ++p) {
        int plane = blockIdx.x * 2 + p;          // b*NC + c (o == c)
        const float4* px = (const float4*)(x + (size_t)plane * 4096);
        float4* po = (float4*)(out + (size_t)plane * 4096);
        const float* ghp = gh + (size_t)plane * 64;
        const float4* gwp = (const float4*)(gw + (size_t)plane * 64);
        #pragma unroll
        for (int i = 0; i < 4; ++i) {
            int f = t + i * 256;
            int row = f >> 4, w4 = f & 15;
            float4 v = px[f];
            float g = ghp[row];
            float4 gv = gwp[w4];
            v.x *= g * gv.x; v.y *= g * gv.y;
            v.z *= g * gv.z; v.w *= g * gv.w;
            po[f] = v;
        }
    }
}

extern "C" void kernel_launch(void* const* d_in, const int* in_sizes, int n_in,
                              void* d_out, int out_size, void* d_ws, size_t ws_size,
                              hipStream_t stream) {
    const float* x   = (const float*)d_in[0];
    const float* w1  = (const float*)d_in[1];
    const float* b1  = (const float*)d_in[2];
    const float* gam = (const float*)d_in[3];
    const float* bet = (const float*)d_in[4];
    const float* mu  = (const float*)d_in[5];
    const float* var = (const float*)d_in[6];
    const float* w2  = (const float*)d_in[7];
    const float* b2  = (const float*)d_in[8];
    const float* w3  = (const float*)d_in[9];
    const float* b3  = (const float*)d_in[10];
    float* ws   = (float*)d_ws;
    float* pool = ws;                       // 32*256*128 = 1,048,576 f
    float* a    = ws + 1048576;             // 32*128*128 =   524,288 f
    float* gh   = ws + 1572864;             // 32*256*64  =   524,288 f
    float* gw   = ws + 2097152;             // 32*256*64  =   524,288 f
    float* out  = (float*)d_out;

    k_pool<<<NPLANES / 4, 256, 0, stream>>>(x, pool);
    k_mlp1<<<dim3(NB, 16), 256, 0, stream>>>(pool, w1, b1, gam, bet, mu, var, a);
    k_gate<<<dim3(NB, 2, 8), 256, 0, stream>>>(a, w2, b2, w3, b3, gh, gw);
    k_apply<<<NPLANES / 2, 256, 0, stream>>>(x, gh, gw, out);
}